// Round 2
// baseline (799.226 us; speedup 1.0000x reference)
//
#include <hip/hip_runtime.h>

typedef float  f32x4_t  __attribute__((ext_vector_type(4)));
typedef __bf16 bf16x8_t __attribute__((ext_vector_type(8)));

#define BS   512
#define Mn   64
#define Kn   32
#define Fn   64
#define ROWS 2048   // Mn*Kn
#define PAD  65
#define NW   8      // waves per block
#define NIT  16     // main-loop iterations per wave (128 tiles / 8 waves)

__global__ __launch_bounds__(512, 4) void gnn_fused(
    const float* __restrict__ z_mk, const float* __restrict__ z_m,
    const float* __restrict__ z_k,  const float* __restrict__ Wedge,
    const float* __restrict__ Wm,   const float* __restrict__ Wk,
    const float* __restrict__ Wself_m, const float* __restrict__ Wself_k,
    const float* __restrict__ Wneigh_m, const float* __restrict__ Wneigh_k,
    float* __restrict__ out0, float* __restrict__ out1, float* __restrict__ out2)
{
    __shared__ __align__(16) float s_wzm[Mn * PAD];          // 4160
    __shared__ __align__(16) float s_wzk[Kn * PAD];          // 2080
    __shared__ __align__(16) float s_r1[Mn * Fn + Kn * Fn];  // 6144 (union region)

    const int tid  = threadIdx.x;
    const int b    = blockIdx.x;
    const int lane = tid & 63;
    const int wave = tid >> 6;     // 0..7
    const int low  = lane & 15;
    const int gr   = lane >> 4;
    const int f    = lane;         // feature index for head/tail
    const int rg   = wave;         // row group for head/tail

    float* s_zm  = s_r1;             // 4096 floats (head phase)
    float* s_zk  = s_r1 + Mn * Fn;   // 2048 floats (head phase)
    float* s_we  = s_r1;             // 4160 floats (frag-build phase)
    float* s_mnm = s_r1;             // 4096 floats (msg phase)
    float* s_mnk = s_r1 + Mn * Fn;   // 2048 floats (msg phase)

    // ---------------- P0: stage z_m, z_k ----------------
    {
        const float4* zms = (const float4*)(z_m + (size_t)b * Mn * Fn);
        float4* zmd = (float4*)s_zm;
        for (int i = tid; i < Mn * Fn / 4; i += 512) zmd[i] = zms[i];
        const float4* zks = (const float4*)(z_k + (size_t)b * Kn * Fn);
        float4* zkd = (float4*)s_zk;
        for (int i = tid; i < Kn * Fn / 4; i += 512) zkd[i] = zks[i];
    }
    __syncthreads();

    // ---------------- P1: head matmuls (fp32) ----------------
    float selfm_reg[8];
    float selfk_reg[4];
    {
        float accA[8], accB[8];
        #pragma unroll
        for (int t = 0; t < 8; ++t) { accA[t] = 0.f; accB[t] = 0.f; }
        for (int c0 = 0; c0 < Fn; c0 += 16) {
            float wA[16], wB[16];
            #pragma unroll
            for (int cc = 0; cc < 16; ++cc) {
                wA[cc] = Wm[(c0 + cc) * Fn + f];
                wB[cc] = Wself_m[(c0 + cc) * Fn + f];
            }
            #pragma unroll
            for (int t = 0; t < 8; ++t) {
                const float* zp = s_zm + (rg + 8 * t) * Fn + c0;
                #pragma unroll
                for (int q = 0; q < 4; ++q) {
                    float4 z = *(const float4*)(zp + q * 4);
                    accA[t] += z.x * wA[4*q] + z.y * wA[4*q+1] + z.z * wA[4*q+2] + z.w * wA[4*q+3];
                    accB[t] += z.x * wB[4*q] + z.y * wB[4*q+1] + z.z * wB[4*q+2] + z.w * wB[4*q+3];
                }
            }
        }
        #pragma unroll
        for (int t = 0; t < 8; ++t) {
            s_wzm[(rg + 8 * t) * PAD + f] = accA[t];
            selfm_reg[t] = accB[t];
        }
    }
    {
        float accA[4], accB[4];
        #pragma unroll
        for (int t = 0; t < 4; ++t) { accA[t] = 0.f; accB[t] = 0.f; }
        for (int c0 = 0; c0 < Fn; c0 += 16) {
            float wA[16], wB[16];
            #pragma unroll
            for (int cc = 0; cc < 16; ++cc) {
                wA[cc] = Wk[(c0 + cc) * Fn + f];
                wB[cc] = Wself_k[(c0 + cc) * Fn + f];
            }
            #pragma unroll
            for (int t = 0; t < 4; ++t) {
                const float* zp = s_zk + (rg + 8 * t) * Fn + c0;
                #pragma unroll
                for (int q = 0; q < 4; ++q) {
                    float4 z = *(const float4*)(zp + q * 4);
                    accA[t] += z.x * wA[4*q] + z.y * wA[4*q+1] + z.z * wA[4*q+2] + z.w * wA[4*q+3];
                    accB[t] += z.x * wB[4*q] + z.y * wB[4*q+1] + z.z * wB[4*q+2] + z.w * wB[4*q+3];
                }
            }
        }
        #pragma unroll
        for (int t = 0; t < 4; ++t) {
            s_wzk[(rg + 8 * t) * PAD + f] = accA[t];
            selfk_reg[t] = accB[t];
        }
    }
    __syncthreads();   // z_m/z_k staging now dead

    // ---------------- P2: stage Wedge (padded) ----------------
    for (int i = tid; i < Fn * Fn; i += 512)
        s_we[(i >> 6) * PAD + (i & 63)] = Wedge[i];
    __syncthreads();

    // ---------------- P3: build B fragments (bf16) ----------------
    bf16x8_t Bf[2][4];
    #pragma unroll
    for (int ks = 0; ks < 2; ++ks)
        #pragma unroll
        for (int n = 0; n < 4; ++n)
            #pragma unroll
            for (int i = 0; i < 8; ++i)
                Bf[ks][n][i] = (__bf16)s_we[(ks * 32 + gr * 8 + i) * PAD + n * 16 + low];
    __syncthreads();   // s_we dead

    // ---------------- P4: zero message accumulators ----------------
    for (int i = tid; i < Mn * Fn + Kn * Fn; i += 512) s_r1[i] = 0.f;
    __syncthreads();

    // ---------------- P5: main edge loop (MFMA), 1-deep prefetch ----------
    float nk[4][4];
    #pragma unroll
    for (int j = 0; j < 4; ++j)
        #pragma unroll
        for (int n = 0; n < 4; ++n) nk[j][n] = 0.f;

    const int p = wave & 1;            // tile parity fixed per wave (stride-8 tiles)
    const size_t browbase = (size_t)b * ROWS;

    // prefetch registers for the current tile's A operand (2 ks * 32B/lane)
    float4 c0a, c0b, c1a, c1b;
    {
        const float* zr = z_mk + (browbase + wave * 16 + low) * 64;
        c0a = *(const float4*)(zr + 0 * 32 + gr * 8);
        c0b = *(const float4*)(zr + 0 * 32 + gr * 8 + 4);
        c1a = *(const float4*)(zr + 1 * 32 + gr * 8);
        c1b = *(const float4*)(zr + 1 * 32 + gr * 8 + 4);
    }

    for (int it = 0; it < NIT; ++it) {
        const int t = wave + NW * it;  // 0..127
        const int rbase = t * 16;
        const int m = t >> 1;

        // issue next tile's loads early (covered by MFMA + epilogue below)
        float4 n0a, n0b, n1a, n1b;
        if (it + 1 < NIT) {
            const float* zrn = z_mk + (browbase + (rbase + NW * 16) + low) * 64;
            n0a = *(const float4*)(zrn + 0 * 32 + gr * 8);
            n0b = *(const float4*)(zrn + 0 * 32 + gr * 8 + 4);
            n1a = *(const float4*)(zrn + 1 * 32 + gr * 8);
            n1b = *(const float4*)(zrn + 1 * 32 + gr * 8 + 4);
        }

        bf16x8_t A[2];
        A[0][0] = (__bf16)c0a.x; A[0][1] = (__bf16)c0a.y;
        A[0][2] = (__bf16)c0a.z; A[0][3] = (__bf16)c0a.w;
        A[0][4] = (__bf16)c0b.x; A[0][5] = (__bf16)c0b.y;
        A[0][6] = (__bf16)c0b.z; A[0][7] = (__bf16)c0b.w;
        A[1][0] = (__bf16)c1a.x; A[1][1] = (__bf16)c1a.y;
        A[1][2] = (__bf16)c1a.z; A[1][3] = (__bf16)c1a.w;
        A[1][4] = (__bf16)c1b.x; A[1][5] = (__bf16)c1b.y;
        A[1][6] = (__bf16)c1b.z; A[1][7] = (__bf16)c1b.w;

        f32x4_t acc[4];
        #pragma unroll
        for (int n = 0; n < 4; ++n) acc[n] = (f32x4_t){0.f, 0.f, 0.f, 0.f};
        #pragma unroll
        for (int ks = 0; ks < 2; ++ks)
            #pragma unroll
            for (int n = 0; n < 4; ++n)
                acc[n] = __builtin_amdgcn_mfma_f32_16x16x32_bf16(A[ks], Bf[ks][n], acc[n], 0, 0, 0);

        #pragma unroll
        for (int n = 0; n < 4; ++n) {
            const int fc = n * 16 + low;
            const float wmv = s_wzm[m * PAD + fc];
            float snm = 0.f;
            #pragma unroll
            for (int j = 0; j < 4; ++j) {
                const int kk = p * 16 + gr * 4 + j;    // == (rbase + gr*4 + j) & 31
                float e = acc[n][j] + wmv + s_wzk[kk * PAD + fc];
                e = e > 0.f ? e : 0.01f * e;
                out0[(browbase + rbase + gr * 4 + j) * 64 + fc] = e;
                nk[j][n] += e;
                snm += e;
            }
            snm += __shfl_xor(snm, 16);
            snm += __shfl_xor(snm, 32);
            if (gr == 0) atomicAdd(&s_mnm[m * Fn + fc], snm);
        }

        c0a = n0a; c0b = n0b; c1a = n1a; c1b = n1b;
    }

    // flush per-lane msg_nk partials
    #pragma unroll
    for (int j = 0; j < 4; ++j)
        #pragma unroll
        for (int n = 0; n < 4; ++n)
            atomicAdd(&s_mnk[(p * 16 + gr * 4 + j) * Fn + n * 16 + low], nk[j][n]);
    __syncthreads();

    // ---------------- P6: tail node updates (fp32) ----------------
    {
        float d[8];
        #pragma unroll
        for (int t = 0; t < 8; ++t) d[t] = 0.f;
        for (int c0 = 0; c0 < Fn; c0 += 16) {
            float w[16];
            #pragma unroll
            for (int cc = 0; cc < 16; ++cc) w[cc] = Wneigh_m[(c0 + cc) * Fn + f];
            #pragma unroll
            for (int t = 0; t < 8; ++t) {
                const float* mp = s_mnm + (rg + 8 * t) * Fn + c0;
                #pragma unroll
                for (int q = 0; q < 4; ++q) {
                    float4 z = *(const float4*)(mp + q * 4);
                    d[t] += z.x * w[4*q] + z.y * w[4*q+1] + z.z * w[4*q+2] + z.w * w[4*q+3];
                }
            }
        }
        #pragma unroll
        for (int t = 0; t < 8; ++t) {
            float v = selfm_reg[t] + d[t] * (1.f / 32.f);
            v = v > 0.f ? v : 0.01f * v;
            out1[(size_t)b * Mn * Fn + (rg + 8 * t) * Fn + f] = v;
        }
    }
    {
        float d[4];
        #pragma unroll
        for (int t = 0; t < 4; ++t) d[t] = 0.f;
        for (int c0 = 0; c0 < Fn; c0 += 16) {
            float w[16];
            #pragma unroll
            for (int cc = 0; cc < 16; ++cc) w[cc] = Wneigh_k[(c0 + cc) * Fn + f];
            #pragma unroll
            for (int t = 0; t < 4; ++t) {
                const float* mp = s_mnk + (rg + 8 * t) * Fn + c0;
                #pragma unroll
                for (int q = 0; q < 4; ++q) {
                    float4 z = *(const float4*)(mp + q * 4);
                    d[t] += z.x * w[4*q] + z.y * w[4*q+1] + z.z * w[4*q+2] + z.w * w[4*q+3];
                }
            }
        }
        #pragma unroll
        for (int t = 0; t < 4; ++t) {
            float v = selfk_reg[t] + d[t] * (1.f / 64.f);
            v = v > 0.f ? v : 0.01f * v;
            out2[(size_t)b * Kn * Fn + (rg + 8 * t) * Fn + f] = v;
        }
    }
}

extern "C" void kernel_launch(void* const* d_in, const int* in_sizes, int n_in,
                              void* d_out, int out_size, void* d_ws, size_t ws_size,
                              hipStream_t stream) {
    const float* z_mk     = (const float*)d_in[0];
    const float* z_m      = (const float*)d_in[1];
    const float* z_k      = (const float*)d_in[2];
    const float* Wedge    = (const float*)d_in[3];
    const float* Wm       = (const float*)d_in[4];
    const float* Wk       = (const float*)d_in[5];
    const float* Wself_m  = (const float*)d_in[6];
    const float* Wself_k  = (const float*)d_in[7];
    const float* Wneigh_m = (const float*)d_in[8];
    const float* Wneigh_k = (const float*)d_in[9];

    float* out0 = (float*)d_out;                       // (512, 2048, 64)
    float* out1 = out0 + (size_t)BS * ROWS * Fn;       // (512, 64, 64)
    float* out2 = out1 + (size_t)BS * Mn * Fn;         // (512, 32, 64)

    gnn_fused<<<BS, 512, 0, stream>>>(z_mk, z_m, z_k, Wedge, Wm, Wk,
                                      Wself_m, Wself_k, Wneigh_m, Wneigh_k,
                                      out0, out1, out2);
}